// Round 11
// baseline (373.557 us; speedup 1.0000x reference)
//
#include <hip/hip_runtime.h>
#include <hip/hip_bf16.h>
#include <stdint.h>

#define M_TRAIN 100000
#define D_DIM   768
#define C_DIM   128
#define NCLUST  500
#define CSIZE   100
#define NCLS    10
#define KSEL    10
#define NCHUNK  4
#define CHUNKN  25000
#define CAND_PER 16
#define NCT     (NCHUNK * CAND_PER)   // 64 candidates per concept
#define FLT_INF 3.402823466e38f

typedef __attribute__((ext_vector_type(8))) short bhalf8;
typedef __attribute__((ext_vector_type(4))) float f32x4;
typedef __attribute__((ext_vector_type(8))) unsigned short ushort8;
typedef __attribute__((ext_vector_type(4))) unsigned short ushort4v;

// ws layout (bytes)
#define WS_KEYT   0LL          // 128*100000*2 = 25,600,000 (bf16 keys)
#define WS_BIMG   25600000LL   // 768*128*2 = 196,608 (12 chunks x 16KB, PLAIN [kc][c][kin])
#define WS_CONT   25796608LL   // conceptT 128*768*4 = 393,216
#define WS_GRAM   26189824LL   // 128*128*4
#define WS_PSCORE 26255360LL   // 2*500*128*4
#define WS_CT     26767360LL   // 768*10*4
#define WS_CAND   26798080LL   // 128*64*4
#define WS_PSUM   26830848LL   // 128*4
#define WS_TSOL   26831360LL   // 128*10*4

#define GSTR 132

static __device__ __forceinline__ unsigned short f2bf(float f) {
    union { float f; unsigned int u; } x; x.f = f;
    unsigned int u = x.u;
    return (unsigned short)((u + 0x7fffu + ((u >> 16) & 1u)) >> 16);
}
// HW packed convert (v_cvt_pk_bf16_f32), RTNE — bit-identical to f2bf for finite vals
static __device__ __forceinline__ unsigned int f2bf2(float lo, float hi) {
    union { __hip_bfloat162 h; unsigned int u; } cv;
    cv.h = __float22bfloat162_rn(make_float2(lo, hi));
    return cv.u;
}

// ======================= kA: score(1000) | prep(384) | gram(64) =======================
__global__ void __launch_bounds__(256) kA(const float* __restrict__ cpt,
        const float* __restrict__ clus, float* __restrict__ conceptT,
        unsigned short* __restrict__ bimg, float* __restrict__ gram,
        float* __restrict__ pscore) {
    int b = blockIdx.x, t = threadIdx.x;
    if (b < 1000) {          // ---- score: partial cluster mean-dot ----
        __shared__ float mean_s[D_DIM];
        int cl = b >> 1, h = b & 1;
        if (t < 192) {
            const float* base = clus + (long)cl * CSIZE * D_DIM + (long)h * 50 * D_DIM + t * 4;
            float ax = 0.f, ay = 0.f, az = 0.f, aw = 0.f;
            for (int s = 0; s < 50; s += 2) {
                float4 v0 = *(const float4*)(base + (long)s * D_DIM);
                float4 v1 = *(const float4*)(base + (long)(s + 1) * D_DIM);
                ax += v0.x + v1.x; ay += v0.y + v1.y;
                az += v0.z + v1.z; aw += v0.w + v1.w;
            }
            const float k = 1.0f / CSIZE;
            mean_s[t * 4 + 0] = ax * k; mean_s[t * 4 + 1] = ay * k;
            mean_s[t * 4 + 2] = az * k; mean_s[t * 4 + 3] = aw * k;
        }
        __syncthreads();
        if (t < 128) {
            float s = 0.f;
            #pragma unroll 4
            for (int d = 0; d < D_DIM; ++d) s += mean_s[d] * cpt[d * 128 + t];
            pscore[h * (NCLUST * 128) + cl * 128 + t] = s;
        }
    } else if (b < 1384) {   // ---- prep: conceptT + PLAIN bf16 B image [kc][c][kin] ----
        int tid = (b - 1000) * 256 + t;        // 0..98303
        int d = tid >> 7, c = tid & 127;
        float v = cpt[tid];
        conceptT[c * D_DIM + d] = v;
        int ofs = (d >> 6) * 16384 + c * 128 + (d & 63) * 2;
        *(unsigned short*)((char*)bimg + ofs) = f2bf(v);
    } else {                 // ---- gram ----
        int c1 = (b - 1384) * 2 + (t >> 7);
        int c2 = t & 127;
        float s = 0.f;
        #pragma unroll 4
        for (int d = 0; d < D_DIM; ++d)
            s += cpt[d * 128 + c1] * cpt[d * 128 + c2];
        gram[c1 * 128 + c2] = s;
    }
}

// ======================= kB roles: cg(10)+ct | old(1) | P(782) =======================
__device__ __forceinline__ float blk_red256(float v, float* buf, int t) {
    #pragma unroll
    for (int m = 32; m > 0; m >>= 1) v += __shfl_xor(v, m);
    if ((t & 63) == 0) buf[t >> 6] = v;
    __syncthreads();
    return buf[0] + buf[1] + buf[2] + buf[3];
}

__device__ __forceinline__ void cg_role(char* smem, const float* __restrict__ gram,
        const float* __restrict__ cpt, const float* __restrict__ whx,
        float* __restrict__ tsol, float* __restrict__ ct,
        float* __restrict__ out_l2new, int j) {
    float* G    = (float*)smem;               // 128*GSTR
    float* p_s  = (float*)(smem + 67584);     // 128
    float* rbuf = (float*)(smem + 68096);     // 12
    int t = threadIdx.x;
    int r = t & 127;
    bool lo = (t < 128);
    if (lo) {
        #pragma unroll 8
        for (int c = 0; c < 128; c += 4)
            *(float4*)&G[r * GSTR + c] = *(const float4*)&gram[r * 128 + c];
    }
    const float* wj = whx + j * D_DIM;
    float rhs = 0.f;
    if (lo) {
        for (int d = 0; d < D_DIM; d += 4)
            rhs += cpt[(d + 0) * 128 + r] * wj[d + 0]
                 + cpt[(d + 1) * 128 + r] * wj[d + 1]
                 + cpt[(d + 2) * 128 + r] * wj[d + 2]
                 + cpt[(d + 3) * 128 + r] * wj[d + 3];
    }
    float x = 0.f, res = rhs, p = rhs;
    if (lo) p_s[r] = p;
    float rr = blk_red256(lo ? res * res : 0.f, rbuf, t);
    __syncthreads();   // G + p_s visible
    if (j == 0) {      // L2new folded here
        float s = 0.f;
        if (lo) {
            #pragma unroll 8
            for (int c = 0; c < 128; ++c) s += G[r * GSTR + c];
            s -= G[r * GSTR + r];
        }
        float tot = blk_red256(s, rbuf + 8, t);
        if (t == 0) out_l2new[0] = tot / 16384.0f;
    }
    for (int it = 0; it < 20; ++it) {
        float q = 0.f;
        if (lo) {
            #pragma unroll 8
            for (int c = 0; c < 128; c += 4) {
                float4 g  = *(const float4*)&G[r * GSTR + c];
                float4 pp = *(const float4*)&p_s[c];
                q += g.x * pp.x + g.y * pp.y + g.z * pp.z + g.w * pp.w;
            }
        }
        float pq = blk_red256(lo ? p * q : 0.f, rbuf + 4, t);
        float alpha = rr / pq;
        x += alpha * p;
        res -= alpha * q;
        float rrn = blk_red256(lo ? res * res : 0.f, rbuf, t);
        float beta = rrn / rr;
        rr = rrn;
        p = res + beta * p;
        if (lo) p_s[r] = p;
        __syncthreads();
    }
    if (lo) tsol[r * NCLS + j] = x;
    // ---- ct tail: ct[d][j] = cpt[d][:] . x ----
    if (lo) p_s[r] = x;
    __syncthreads();
    for (int d = t; d < D_DIM; d += 256) {
        const float* crow = cpt + d * 128;
        float s = 0.f;
        #pragma unroll 8
        for (int c = 0; c < 128; c += 4) {
            float4 cc = *(const float4*)(crow + c);
            float4 xx = *(const float4*)&p_s[c];
            s += cc.x * xx.x + cc.y * xx.y + cc.z * xx.z + cc.w * xx.w;
        }
        ct[d * NCLS + j] = s;
    }
}

__device__ __forceinline__ void old_role(char* smem, const float* __restrict__ pscore,
        const float* __restrict__ gram, float* __restrict__ out01) {
    float* ss2     = (float*)smem;             // 256
    float* sm2     = (float*)(smem + 1024);    // 256
    float* rcn_s   = (float*)(smem + 2048);    // 128
    float* wcomb   = (float*)(smem + 2560);    // 128
    float* redA    = (float*)(smem + 3072);    // 128
    float* redB    = (float*)(smem + 3584);    // 128
    float* wred4   = (float*)(smem + 4096);    // 4
    float* trace_s = (float*)(smem + 4112);    // 1
    const float* p0 = pscore;
    const float* p1 = pscore + NCLUST * 128;
    int t = threadIdx.x;
    int c = t & 127, w2 = t >> 7;
    if (t < 128) rcn_s[t] = 1.0f / fmaxf(sqrtf(gram[t * 129]), 1e-12f);
    __syncthreads();
    float rc = rcn_s[c];
    float ss = 0.f, sm = 0.f;
    for (int bb = 0; bb < 25; ++bb) {
        float a[10];
        #pragma unroll
        for (int k = 0; k < 10; ++k) {
            int cl = w2 + 2 * (10 * bb + k);
            a[k] = p0[cl * 128 + c] + p1[cl * 128 + c];
        }
        #pragma unroll
        for (int k = 0; k < 10; ++k) { float v = fabsf(a[k]) * rc; ss += v * v; sm += v; }
    }
    ss2[w2 * 128 + c] = ss; sm2[w2 * 128 + c] = sm;
    __syncthreads();
    if (t < 128) {
        float S = ss2[t] + ss2[128 + t];
        float M = sm2[t] + sm2[128 + t];
        float nn = fmaxf(sqrtf(S), 1e-12f);
        float iv = 1.0f / nn;
        wcomb[t] = rcn_s[t] * iv;
        redA[t] = M * iv;
        redB[t] = S * iv * iv;
    }
    __syncthreads();
    if (t < 64) {
        float a = redA[t] + redA[t + 64];
        float b2 = redB[t] + redB[t + 64];
        #pragma unroll
        for (int m = 32; m > 0; m >>= 1) { a += __shfl_xor(a, m); b2 += __shfl_xor(b2, m); }
        if (t == 0) { out01[0] = a; trace_s[0] = b2; }
    }
    __syncthreads();
    int w = t >> 6, lane = t & 63;
    float wc0 = wcomb[lane], wc1 = wcomb[lane + 64];
    float rsq = 0.f;
    for (int bb = 0; bb < 25; ++bb) {
        float a0[5], a1[5];
        #pragma unroll
        for (int k = 0; k < 5; ++k) {
            int cl = w + 4 * (5 * bb + k);
            a0[k] = p0[cl * 128 + lane] + p1[cl * 128 + lane];
            a1[k] = p0[cl * 128 + 64 + lane] + p1[cl * 128 + 64 + lane];
        }
        #pragma unroll
        for (int k = 0; k < 5; ++k) {
            float v = fabsf(a0[k]) * wc0 + fabsf(a1[k]) * wc1;
            #pragma unroll
            for (int m = 32; m > 0; m >>= 1) v += __shfl_xor(v, m);
            if (lane == 0) rsq += v * v;
        }
    }
    if (lane == 0) wred4[w] = rsq;
    __syncthreads();
    if (t == 0) out01[1] = wred4[0] + wred4[1] + wred4[2] + wred4[3] - trace_s[0];
}

// ------- P: barrier-free main loop. Wave owns 32 rows x all 128 cols. -------
// A: global->reg (3-deep), cvt in-reg; B: plain bimg L2->reg (2-deep). No LDS,
// no barriers until the single epilogue staging barrier. Per-register vmcnt
// dependencies let the compiler software-pipeline freely.
__device__ __forceinline__ void P_role(char* smem, const float* __restrict__ E,
        const unsigned short* __restrict__ bimg, unsigned short* __restrict__ keyT,
        int blk) {
    unsigned short* cst = (unsigned short*)smem;   // epilogue overlay [128][136]
    int t = threadIdx.x;
    int lane = t & 63, w = t >> 6;
    int r15 = lane & 15, kg = lane >> 4;
    int rowbase = blk * 128;
    int wrow = rowbase + w * 32;                   // wave's global row base

    f32x4 acc[2][8];
    #pragma unroll
    for (int mt = 0; mt < 2; ++mt)
        #pragma unroll
        for (int n = 0; n < 8; ++n) acc[mt][n] = (f32x4){0.f, 0.f, 0.f, 0.f};
    float esq[2] = {0.f, 0.f};

    float4 Ab[3][2][2];    // [set][mt][half] — 3-deep A staging
    bhalf8 Bb[2][8];       // [set][n]        — 2-deep B staging

    const float* Arow0 = E + (long)(wrow + r15) * D_DIM + kg * 8;
    const float* Arow1 = E + (long)(wrow + 16 + r15) * D_DIM + kg * 8;
    bool v0 = (wrow + r15) < M_TRAIN;
    bool v1 = (wrow + 16 + r15) < M_TRAIN;
    const float4 z4 = make_float4(0.f, 0.f, 0.f, 0.f);

    auto issueA = [&](int ks) {
        int s = ks % 3;
        if (v0) { Ab[s][0][0] = *(const float4*)(Arow0 + ks * 32);
                  Ab[s][0][1] = *(const float4*)(Arow0 + ks * 32 + 4); }
        else    { Ab[s][0][0] = z4; Ab[s][0][1] = z4; }
        if (v1) { Ab[s][1][0] = *(const float4*)(Arow1 + ks * 32);
                  Ab[s][1][1] = *(const float4*)(Arow1 + ks * 32 + 4); }
        else    { Ab[s][1][0] = z4; Ab[s][1][1] = z4; }
    };
    auto issueB = [&](int ks) {
        int s = ks & 1;
        const char* bs = (const char*)bimg + (ks >> 1) * 16384 + (ks & 1) * 64 + kg * 16;
        #pragma unroll
        for (int n = 0; n < 8; ++n)
            Bb[s][n] = *(const bhalf8*)(bs + (n * 16 + r15) * 128);
    };

    issueA(0); issueA(1); issueB(0);
    #pragma unroll
    for (int ks = 0; ks < 12; ++ks) {
        if (ks + 2 < 12) issueA(ks + 2);
        if (ks + 1 < 12) issueB(ks + 1);
        int s = ks % 3, sb = ks & 1;
        bhalf8 af[2];
        #pragma unroll
        for (int mt = 0; mt < 2; ++mt) {
            float4 u0 = Ab[s][mt][0], u1 = Ab[s][mt][1];
            esq[mt] += u0.x*u0.x + u0.y*u0.y + u0.z*u0.z + u0.w*u0.w
                     + u1.x*u1.x + u1.y*u1.y + u1.z*u1.z + u1.w*u1.w;
            union { bhalf8 v; unsigned int u[4]; } h;
            h.u[0] = f2bf2(u0.x, u0.y);
            h.u[1] = f2bf2(u0.z, u0.w);
            h.u[2] = f2bf2(u1.x, u1.y);
            h.u[3] = f2bf2(u1.z, u1.w);
            af[mt] = h.v;
        }
        #pragma unroll
        for (int mt = 0; mt < 2; ++mt)
            #pragma unroll
            for (int n = 0; n < 8; ++n)
                acc[mt][n] = __builtin_amdgcn_mfma_f32_16x16x32_bf16(af[mt], Bb[sb][n], acc[mt][n], 0, 0, 0);
    }
    // full-row e_sq: reduce across the 4 k-groups holding the same row
    #pragma unroll
    for (int mt = 0; mt < 2; ++mt) {
        esq[mt] += __shfl_xor(esq[mt], 16);
        esq[mt] += __shfl_xor(esq[mt], 32);
    }
    // epilogue: stage C-tile (bf16 keys) into LDS, column-major rows
    #pragma unroll
    for (int mt = 0; mt < 2; ++mt) {
        int r0 = w * 32 + mt * 16 + kg * 4;
        float e0 = __shfl(esq[mt], kg * 4 + 0);
        float e1 = __shfl(esq[mt], kg * 4 + 1);
        float e2 = __shfl(esq[mt], kg * 4 + 2);
        float e3 = __shfl(esq[mt], kg * 4 + 3);
        #pragma unroll
        for (int n = 0; n < 8; ++n) {
            int c = n * 16 + r15;
            union { ushort4v v; unsigned int u[2]; } kv;
            kv.u[0] = f2bf2(e0 - 2.f * acc[mt][n][0], e1 - 2.f * acc[mt][n][1]);
            kv.u[1] = f2bf2(e2 - 2.f * acc[mt][n][2], e3 - 2.f * acc[mt][n][3]);
            *(ushort4v*)(cst + c * 136 + r0) = kv.v;
        }
    }
    __syncthreads();    // the ONLY barrier: cross-wave cst handoff
    #pragma unroll
    for (int it = 0; it < 8; ++it) {
        int c = w * 32 + it * 4 + kg;
        int r = r15 * 8;
        if (rowbase + r < M_TRAIN) {
            ushort8 v = *(const ushort8*)(cst + c * 136 + r);
            *(ushort8*)(keyT + (long)c * M_TRAIN + rowbase + r) = v;
        }
    }
}

__global__ void __launch_bounds__(256, 2) kB(const float* __restrict__ E,
        const unsigned short* __restrict__ bimg, unsigned short* __restrict__ keyT,
        const float* __restrict__ gram, const float* __restrict__ cpt,
        const float* __restrict__ whx, float* __restrict__ tsol,
        float* __restrict__ ct, float* __restrict__ out_scal,
        const float* __restrict__ pscore) {
    __shared__ __align__(16) char smem[68160];
    int b = blockIdx.x;
    if (b < 10)       cg_role(smem, gram, cpt, whx, tsol, ct, out_scal + 3, b);
    else if (b == 10) old_role(smem, pscore, gram, out_scal);
    else              P_role(smem, E, bimg, keyT, b - 11);
}

// ======================= kC: select(512) | ypred(512) =======================
__global__ void __launch_bounds__(256) kC(const unsigned short* __restrict__ keyT,
        int* __restrict__ cand, const float* __restrict__ te,
        const float* __restrict__ ct, const float* __restrict__ bhx,
        float* __restrict__ out) {
    __shared__ __align__(16) char smem[30720];
    int b = blockIdx.x, t = threadIdx.x;
    if (b < 512) {     // ---- select: per-(concept, quarter) top-16 ----
        int* sk  = (int*)smem;            // 2048
        int* si  = (int*)(smem + 8192);   // 2048
        int* wk  = (int*)(smem + 16384);
        int* wi  = (int*)(smem + 16400);
        int* wsl = (int*)(smem + 16416);
        int c = b >> 2, h = b & 3;
        const unsigned short* col = keyT + (long)c * M_TRAIN + h * CHUNKN;
        int base = h * CHUNKN;
        int tk[8], ti[8];
        #pragma unroll
        for (int i = 0; i < 8; ++i) { tk[i] = 0x7fffffff; ti[i] = 0x7fffffff; }
        for (int i = t; i < CHUNKN / 8; i += 256) {
            ushort8 v = *(const ushort8*)(col + i * 8);
            int idx = base + i * 8;
            #pragma unroll
            for (int q = 0; q < 8; ++q) {
                int cv = (int)v[q]; int ci = idx + q;
                if (cv < tk[7] || (cv == tk[7] && ci < ti[7])) {
                    #pragma unroll
                    for (int jj = 0; jj < 8; ++jj) {
                        bool sw = (cv < tk[jj]) || (cv == tk[jj] && ci < ti[jj]);
                        int ok = tk[jj]; int oi = ti[jj];
                        if (sw) { tk[jj] = cv; ti[jj] = ci; cv = ok; ci = oi; }
                    }
                }
            }
        }
        #pragma unroll
        for (int i = 0; i < 8; ++i) { sk[t * 8 + i] = tk[i]; si[t * 8 + i] = ti[i]; }
        __syncthreads();
        int lane = t & 63, w = t >> 6;
        for (int sel = 0; sel < CAND_PER; ++sel) {
            int bk = 0x7fffffff, bi = 0x7fffffff, bs = -1;
            #pragma unroll
            for (int i = 0; i < 8; ++i) {
                int s = t * 8 + i;
                int v = sk[s];
                if (v < bk || (v == bk && si[s] < bi)) { bk = v; bi = si[s]; bs = s; }
            }
            #pragma unroll
            for (int m = 32; m > 0; m >>= 1) {
                int ok = __shfl_xor(bk, m); int oi = __shfl_xor(bi, m); int os = __shfl_xor(bs, m);
                if (ok < bk || (ok == bk && oi < bi)) { bk = ok; bi = oi; bs = os; }
            }
            if (lane == 0) { wk[w] = bk; wi[w] = bi; wsl[w] = bs; }
            __syncthreads();
            if (t == 0) {
                int fk = wk[0], fi = wi[0], fs = wsl[0];
                for (int i = 1; i < 4; ++i)
                    if (wk[i] < fk || (wk[i] == fk && wi[i] < fi)) { fk = wk[i]; fi = wi[i]; fs = wsl[i]; }
                cand[(c * NCHUNK + h) * CAND_PER + sel] = fi;
                sk[fs] = 0x7fffffff; si[fs] = 0x7fffffff;
            }
            __syncthreads();
        }
    } else {           // ---- ypred ----
        float* ctT = (float*)smem;   // [NCLS][D_DIM]
        for (int o = t; o < D_DIM * NCLS; o += 256) {
            int j = o / D_DIM, d = o % D_DIM;
            ctT[j * D_DIM + d] = ct[d * NCLS + j];
        }
        __syncthreads();
        int r = t >> 5, l = t & 31;
        long row = (long)(b - 512) * 8 + r;
        const float* er = te + row * D_DIM;
        float acc[NCLS];
        #pragma unroll
        for (int j = 0; j < NCLS; ++j) acc[j] = 0.f;
        for (int d0 = l * 4; d0 < D_DIM; d0 += 128) {
            float4 e = *(const float4*)(er + d0);
            #pragma unroll
            for (int j = 0; j < NCLS; ++j) {
                float4 cc = *(const float4*)(&ctT[j * D_DIM + d0]);
                acc[j] += e.x*cc.x + e.y*cc.y + e.z*cc.z + e.w*cc.w;
            }
        }
        #pragma unroll
        for (int j = 0; j < NCLS; ++j) {
            #pragma unroll
            for (int m = 16; m > 0; m >>= 1) acc[j] += __shfl_xor(acc[j], m);
        }
        if (l == 0) {
            #pragma unroll
            for (int j = 0; j < NCLS; ++j) out[row * NCLS + j] = acc[j] + bhx[j];
        }
    }
}

// ======================= kD: refine(128) =======================
__global__ void __launch_bounds__(256) kD(const float* __restrict__ E,
        const float* __restrict__ conceptT, const int* __restrict__ cand,
        float* __restrict__ psum) {
    __shared__ float skey[NCT], sdot[NCT];
    __shared__ int sidx[NCT];
    int c = blockIdx.x, t = threadIdx.x;
    int g = t >> 2, l4 = t & 3;
    int idx = cand[c * NCT + g];
    const float* er = E + (long)idx * D_DIM;
    const float* cr = conceptT + c * D_DIM;
    float dot = 0.f, ss = 0.f;
    for (int d0 = l4 * 4; d0 < D_DIM; d0 += 16) {
        float4 e = *(const float4*)(er + d0);
        float4 cc = *(const float4*)(cr + d0);
        dot += e.x*cc.x + e.y*cc.y + e.z*cc.z + e.w*cc.w;
        ss  += e.x*e.x + e.y*e.y + e.z*e.z + e.w*e.w;
    }
    dot += __shfl_xor(dot, 1); dot += __shfl_xor(dot, 2);
    ss  += __shfl_xor(ss, 1);  ss  += __shfl_xor(ss, 2);
    if (l4 == 0) { skey[g] = ss - 2.f * dot; sdot[g] = dot; sidx[g] = idx; }
    __syncthreads();
    if (t == 0) {
        float sum = 0.f;
        unsigned long long used = 0ull;
        for (int s = 0; s < KSEL; ++s) {
            float bk = FLT_INF; int bi = 0x7fffffff, bs = 0;
            for (int i = 0; i < NCT; ++i) {
                if ((used >> i) & 1ull) continue;
                if (skey[i] < bk || (skey[i] == bk && sidx[i] < bi)) { bk = skey[i]; bi = sidx[i]; bs = i; }
            }
            used |= (1ull << bs);
            sum += sdot[bs];
        }
        psum[c] = sum;
    }
}

__global__ void k_finalize(const float* __restrict__ psum, float* __restrict__ out2) {
    __shared__ float red[128];
    int t = threadIdx.x;
    red[t] = psum[t];
    __syncthreads();
    for (int s = 64; s > 0; s >>= 1) { if (t < s) red[t] += red[t + s]; __syncthreads(); }
    if (t == 0) out2[0] = red[0] * (1.0f / (C_DIM * KSEL));
}

extern "C" void kernel_launch(void* const* d_in, const int* in_sizes, int n_in,
                              void* d_out, int out_size, void* d_ws, size_t ws_size,
                              hipStream_t stream) {
    (void)in_sizes; (void)n_in; (void)out_size; (void)ws_size;
    const float* te   = (const float*)d_in[0];  // 4096x768
    const float* cpt  = (const float*)d_in[1];  // 768x128
    const float* clus = (const float*)d_in[2];  // 500x100x768
    const float* tes  = (const float*)d_in[3];  // 100000x768
    const float* whx  = (const float*)d_in[4];  // 10x768
    const float* bhx  = (const float*)d_in[5];  // 10
    float* out = (float*)d_out;                 // 40960 y_pred + 4 scalars
    char* ws = (char*)d_ws;
    unsigned short* keyT  = (unsigned short*)(ws + WS_KEYT);
    unsigned short* bimg  = (unsigned short*)(ws + WS_BIMG);
    float* conceptT       = (float*)(ws + WS_CONT);
    float* gram           = (float*)(ws + WS_GRAM);
    float* pscore         = (float*)(ws + WS_PSCORE);
    float* ct             = (float*)(ws + WS_CT);
    int* cand             = (int*)(ws + WS_CAND);
    float* psum           = (float*)(ws + WS_PSUM);
    float* tsol           = (float*)(ws + WS_TSOL);

    kA<<<dim3(1448), dim3(256), 0, stream>>>(cpt, clus, conceptT, bimg, gram, pscore);
    kB<<<dim3(793),  dim3(256), 0, stream>>>(tes, bimg, keyT, gram, cpt, whx, tsol, ct,
                                             out + 40960, pscore);
    kC<<<dim3(1024), dim3(256), 0, stream>>>(keyT, cand, te, ct, bhx, out);
    kD<<<dim3(128),  dim3(256), 0, stream>>>(tes, conceptT, cand, psum);
    k_finalize<<<dim3(1), dim3(128), 0, stream>>>(psum, out + 40962);
}

// Round 12
// 329.517 us; speedup vs baseline: 1.1337x; 1.1337x over previous
//
#include <hip/hip_runtime.h>
#include <hip/hip_bf16.h>
#include <stdint.h>

#define M_TRAIN 100000
#define D_DIM   768
#define C_DIM   128
#define NCLUST  500
#define CSIZE   100
#define NCLS    10
#define KSEL    10
#define NCHUNK  4
#define CHUNKN  25000
#define CAND_PER 16
#define NCT     (NCHUNK * CAND_PER)   // 64 candidates per concept
#define FLT_INF 3.402823466e38f

typedef __attribute__((ext_vector_type(8))) short bhalf8;
typedef __attribute__((ext_vector_type(4))) float f32x4;
typedef __attribute__((ext_vector_type(8))) unsigned short ushort8;
typedef __attribute__((ext_vector_type(4))) unsigned short ushort4v;

// ws layout (bytes)
#define WS_KEYT   0LL          // 128*100000*2 = 25,600,000 (bf16 keys)
#define WS_BIMG   25600000LL   // 768*128*2 = 196,608 (12 chunks x 16KB, pre-swizzled)
#define WS_CONT   25796608LL   // conceptT 128*768*4 = 393,216
#define WS_GRAM   26189824LL   // 128*128*4
#define WS_PSCORE 26255360LL   // 2*500*128*4
#define WS_CT     26767360LL   // 768*10*4
#define WS_CAND   26798080LL   // 128*64*4
#define WS_PSUM   26830848LL   // 128*4
#define WS_TSOL   26831360LL   // 128*10*4

#define GSTR 132

static __device__ __forceinline__ unsigned short f2bf(float f) {
    union { float f; unsigned int u; } x; x.f = f;
    unsigned int u = x.u;
    return (unsigned short)((u + 0x7fffu + ((u >> 16) & 1u)) >> 16);
}
// HW packed convert (v_cvt_pk_bf16_f32), RTNE — bit-identical to f2bf for finite vals
static __device__ __forceinline__ unsigned int f2bf2(float lo, float hi) {
    union { __hip_bfloat162 h; unsigned int u; } cv;
    cv.h = __float22bfloat162_rn(make_float2(lo, hi));
    return cv.u;
}

// ======================= kA: score(1000) | prep(384) | gram(64) =======================
__global__ void __launch_bounds__(256) kA(const float* __restrict__ cpt,
        const float* __restrict__ clus, float* __restrict__ conceptT,
        unsigned short* __restrict__ bimg, float* __restrict__ gram,
        float* __restrict__ pscore) {
    int b = blockIdx.x, t = threadIdx.x;
    if (b < 1000) {          // ---- score: partial cluster mean-dot ----
        __shared__ float mean_s[D_DIM];
        int cl = b >> 1, h = b & 1;
        if (t < 192) {
            const float* base = clus + (long)cl * CSIZE * D_DIM + (long)h * 50 * D_DIM + t * 4;
            float ax = 0.f, ay = 0.f, az = 0.f, aw = 0.f;
            for (int s = 0; s < 50; s += 2) {
                float4 v0 = *(const float4*)(base + (long)s * D_DIM);
                float4 v1 = *(const float4*)(base + (long)(s + 1) * D_DIM);
                ax += v0.x + v1.x; ay += v0.y + v1.y;
                az += v0.z + v1.z; aw += v0.w + v1.w;
            }
            const float k = 1.0f / CSIZE;
            mean_s[t * 4 + 0] = ax * k; mean_s[t * 4 + 1] = ay * k;
            mean_s[t * 4 + 2] = az * k; mean_s[t * 4 + 3] = aw * k;
        }
        __syncthreads();
        if (t < 128) {
            float s = 0.f;
            #pragma unroll 4
            for (int d = 0; d < D_DIM; ++d) s += mean_s[d] * cpt[d * 128 + t];
            pscore[h * (NCLUST * 128) + cl * 128 + t] = s;
        }
    } else if (b < 1384) {   // ---- prep: conceptT + pre-swizzled bf16 B image ----
        int tid = (b - 1000) * 256 + t;        // 0..98303
        int d = tid >> 7, c = tid & 127;
        float v = cpt[tid];
        conceptT[c * D_DIM + d] = v;
        int kc = d >> 6, kin = d & 63;
        int ofs = kc * 16384 + (((c << 7) + (kin << 1)) ^ ((c & 7) << 4));
        *(unsigned short*)((char*)bimg + ofs) = f2bf(v);
    } else {                 // ---- gram ----
        int c1 = (b - 1384) * 2 + (t >> 7);
        int c2 = t & 127;
        float s = 0.f;
        #pragma unroll 4
        for (int d = 0; d < D_DIM; ++d)
            s += cpt[d * 128 + c1] * cpt[d * 128 + c2];
        gram[c1 * 128 + c2] = s;
    }
}

// ======================= kB roles: cg(10)+ct | old(1) | P(782) =======================
__device__ __forceinline__ float blk_red256(float v, float* buf, int t) {
    #pragma unroll
    for (int m = 32; m > 0; m >>= 1) v += __shfl_xor(v, m);
    if ((t & 63) == 0) buf[t >> 6] = v;
    __syncthreads();
    return buf[0] + buf[1] + buf[2] + buf[3];
}

__device__ __forceinline__ void cg_role(char* smem, const float* __restrict__ gram,
        const float* __restrict__ cpt, const float* __restrict__ whx,
        float* __restrict__ tsol, float* __restrict__ ct,
        float* __restrict__ out_l2new, int j) {
    float* G    = (float*)smem;               // 128*GSTR
    float* p_s  = (float*)(smem + 67584);     // 128
    float* rbuf = (float*)(smem + 68096);     // 12
    int t = threadIdx.x;
    int r = t & 127;
    bool lo = (t < 128);
    if (lo) {
        #pragma unroll 8
        for (int c = 0; c < 128; c += 4)
            *(float4*)&G[r * GSTR + c] = *(const float4*)&gram[r * 128 + c];
    }
    const float* wj = whx + j * D_DIM;
    float rhs = 0.f;
    if (lo) {
        for (int d = 0; d < D_DIM; d += 4)
            rhs += cpt[(d + 0) * 128 + r] * wj[d + 0]
                 + cpt[(d + 1) * 128 + r] * wj[d + 1]
                 + cpt[(d + 2) * 128 + r] * wj[d + 2]
                 + cpt[(d + 3) * 128 + r] * wj[d + 3];
    }
    float x = 0.f, res = rhs, p = rhs;
    if (lo) p_s[r] = p;
    float rr = blk_red256(lo ? res * res : 0.f, rbuf, t);
    __syncthreads();   // G + p_s visible
    if (j == 0) {      // L2new folded here
        float s = 0.f;
        if (lo) {
            #pragma unroll 8
            for (int c = 0; c < 128; ++c) s += G[r * GSTR + c];
            s -= G[r * GSTR + r];
        }
        float tot = blk_red256(s, rbuf + 8, t);
        if (t == 0) out_l2new[0] = tot / 16384.0f;
    }
    for (int it = 0; it < 20; ++it) {
        float q = 0.f;
        if (lo) {
            #pragma unroll 8
            for (int c = 0; c < 128; c += 4) {
                float4 g  = *(const float4*)&G[r * GSTR + c];
                float4 pp = *(const float4*)&p_s[c];
                q += g.x * pp.x + g.y * pp.y + g.z * pp.z + g.w * pp.w;
            }
        }
        float pq = blk_red256(lo ? p * q : 0.f, rbuf + 4, t);
        float alpha = rr / pq;
        x += alpha * p;
        res -= alpha * q;
        float rrn = blk_red256(lo ? res * res : 0.f, rbuf, t);
        float beta = rrn / rr;
        rr = rrn;
        p = res + beta * p;
        if (lo) p_s[r] = p;
        __syncthreads();
    }
    if (lo) tsol[r * NCLS + j] = x;
    // ---- ct tail: ct[d][j] = cpt[d][:] . x ----
    if (lo) p_s[r] = x;
    __syncthreads();
    for (int d = t; d < D_DIM; d += 256) {
        const float* crow = cpt + d * 128;
        float s = 0.f;
        #pragma unroll 8
        for (int c = 0; c < 128; c += 4) {
            float4 cc = *(const float4*)(crow + c);
            float4 xx = *(const float4*)&p_s[c];
            s += cc.x * xx.x + cc.y * xx.y + cc.z * xx.z + cc.w * xx.w;
        }
        ct[d * NCLS + j] = s;
    }
}

__device__ __forceinline__ void old_role(char* smem, const float* __restrict__ pscore,
        const float* __restrict__ gram, float* __restrict__ out01) {
    float* ss2     = (float*)smem;             // 256
    float* sm2     = (float*)(smem + 1024);    // 256
    float* rcn_s   = (float*)(smem + 2048);    // 128
    float* wcomb   = (float*)(smem + 2560);    // 128
    float* redA    = (float*)(smem + 3072);    // 128
    float* redB    = (float*)(smem + 3584);    // 128
    float* wred4   = (float*)(smem + 4096);    // 4
    float* trace_s = (float*)(smem + 4112);    // 1
    const float* p0 = pscore;
    const float* p1 = pscore + NCLUST * 128;
    int t = threadIdx.x;
    int c = t & 127, w2 = t >> 7;
    if (t < 128) rcn_s[t] = 1.0f / fmaxf(sqrtf(gram[t * 129]), 1e-12f);
    __syncthreads();
    float rc = rcn_s[c];
    float ss = 0.f, sm = 0.f;
    for (int bb = 0; bb < 25; ++bb) {
        float a[10];
        #pragma unroll
        for (int k = 0; k < 10; ++k) {
            int cl = w2 + 2 * (10 * bb + k);
            a[k] = p0[cl * 128 + c] + p1[cl * 128 + c];
        }
        #pragma unroll
        for (int k = 0; k < 10; ++k) { float v = fabsf(a[k]) * rc; ss += v * v; sm += v; }
    }
    ss2[w2 * 128 + c] = ss; sm2[w2 * 128 + c] = sm;
    __syncthreads();
    if (t < 128) {
        float S = ss2[t] + ss2[128 + t];
        float M = sm2[t] + sm2[128 + t];
        float nn = fmaxf(sqrtf(S), 1e-12f);
        float iv = 1.0f / nn;
        wcomb[t] = rcn_s[t] * iv;
        redA[t] = M * iv;
        redB[t] = S * iv * iv;
    }
    __syncthreads();
    if (t < 64) {
        float a = redA[t] + redA[t + 64];
        float b2 = redB[t] + redB[t + 64];
        #pragma unroll
        for (int m = 32; m > 0; m >>= 1) { a += __shfl_xor(a, m); b2 += __shfl_xor(b2, m); }
        if (t == 0) { out01[0] = a; trace_s[0] = b2; }
    }
    __syncthreads();
    int w = t >> 6, lane = t & 63;
    float wc0 = wcomb[lane], wc1 = wcomb[lane + 64];
    float rsq = 0.f;
    for (int bb = 0; bb < 25; ++bb) {
        float a0[5], a1[5];
        #pragma unroll
        for (int k = 0; k < 5; ++k) {
            int cl = w + 4 * (5 * bb + k);
            a0[k] = p0[cl * 128 + lane] + p1[cl * 128 + lane];
            a1[k] = p0[cl * 128 + 64 + lane] + p1[cl * 128 + 64 + lane];
        }
        #pragma unroll
        for (int k = 0; k < 5; ++k) {
            float v = fabsf(a0[k]) * wc0 + fabsf(a1[k]) * wc1;
            #pragma unroll
            for (int m = 32; m > 0; m >>= 1) v += __shfl_xor(v, m);
            if (lane == 0) rsq += v * v;
        }
    }
    if (lane == 0) wred4[w] = rsq;
    __syncthreads();
    if (t == 0) out01[1] = wred4[0] + wred4[1] + wred4[2] + wred4[3] - trace_s[0];
}

// ------- P: 2-deep reg-staged pipeline (X/Y sets), LDS dbuf, 1 barrier/K-step -------
// vmcnt-wait for K-step k's loads lands one full iteration after issue (~2 MFMA
// phases ≈ 700-900cy) instead of ~350cy -> HBM latency nearly fully hidden.
__device__ __forceinline__ void P_role(char* smem, const float* __restrict__ E,
        const unsigned short* __restrict__ bimg, unsigned short* __restrict__ keyT,
        int blk) {
    char* lds = smem;                           // A dbuf 0..32K, B dbuf 32K..64K
    float* esq_s = (float*)(smem + 65536);      // 128
    unsigned short* cst = (unsigned short*)lds; // epilogue overlay [128][136]

    int t = threadIdx.x;
    int rowbase = blk * 128;
    int lane = t & 63, w = t >> 6;
    int wr = w >> 1, wc = w & 1;
    f32x4 acc[4][4];
    #pragma unroll
    for (int m = 0; m < 4; ++m)
        #pragma unroll
        for (int n = 0; n < 4; ++n) acc[m][n] = (f32x4){0.f, 0.f, 0.f, 0.f};
    float esq_p[4] = {0.f, 0.f, 0.f, 0.f};
    int g = t >> 3, k8 = t & 7;
    int kb = (lane >> 4) * 16;

    float4 xa0[4], xa1[4]; bhalf8 xb[4];   // X staging set
    float4 ya0[4], ya1[4]; bhalf8 yb[4];   // Y staging set

    auto issue = [&](int ks, float4* A0, float4* A1, bhalf8* B) {
        #pragma unroll
        for (int p = 0; p < 4; ++p) {
            int grow = rowbase + 32 * p + g;
            if (grow < M_TRAIN) {
                const float* src = E + (long)grow * D_DIM + ks * 64 + k8 * 8;
                A0[p] = *(const float4*)(src);
                A1[p] = *(const float4*)(src + 4);
            } else {
                A0[p] = make_float4(0.f, 0.f, 0.f, 0.f);
                A1[p] = make_float4(0.f, 0.f, 0.f, 0.f);
            }
        }
        const char* bs = (const char*)bimg + ks * 16384;
        #pragma unroll
        for (int i = 0; i < 4; ++i)
            B[i] = *(const bhalf8*)(bs + (i * 256 + t) * 16);
    };
    auto writeb = [&](int buf, const float4* A0, const float4* A1, const bhalf8* B) {
        char* Ab = lds + buf * 16384;
        char* Bb = lds + 32768 + buf * 16384;
        #pragma unroll
        for (int p = 0; p < 4; ++p) {
            int row = 32 * p + g;
            float4 v0 = A0[p], v1 = A1[p];
            esq_p[p] += v0.x*v0.x + v0.y*v0.y + v0.z*v0.z + v0.w*v0.w
                      + v1.x*v1.x + v1.y*v1.y + v1.z*v1.z + v1.w*v1.w;
            union { bhalf8 v; unsigned int u[4]; } h;
            h.u[0] = f2bf2(v0.x, v0.y);
            h.u[1] = f2bf2(v0.z, v0.w);
            h.u[2] = f2bf2(v1.x, v1.y);
            h.u[3] = f2bf2(v1.z, v1.w);
            int byte = (row * 128 + k8 * 16) ^ ((row & 7) << 4);
            *(bhalf8*)(Ab + byte) = h.v;
        }
        #pragma unroll
        for (int i = 0; i < 4; ++i)
            *(bhalf8*)(Bb + (i * 256 + t) * 16) = B[i];
    };
    auto mfma_step = [&](int buf) {
        const char* Ab = lds + buf * 16384;
        const char* Bb = lds + 32768 + buf * 16384;
        bhalf8 bf[4][2];
        #pragma unroll
        for (int n = 0; n < 4; ++n) {
            int c = wc * 64 + n * 16 + (lane & 15);
            int b0 = c * 128, sw = (c & 7) << 4;
            bf[n][0] = *(const bhalf8*)(Bb + ((b0 + kb) ^ sw));
            bf[n][1] = *(const bhalf8*)(Bb + ((b0 + kb + 64) ^ sw));
        }
        #pragma unroll
        for (int m = 0; m < 4; ++m) {
            int row = wr * 64 + m * 16 + (lane & 15);
            int b0 = row * 128, sw = (row & 7) << 4;
            bhalf8 af0 = *(const bhalf8*)(Ab + ((b0 + kb) ^ sw));
            bhalf8 af1 = *(const bhalf8*)(Ab + ((b0 + kb + 64) ^ sw));
            #pragma unroll
            for (int n = 0; n < 4; ++n) {
                acc[m][n] = __builtin_amdgcn_mfma_f32_16x16x32_bf16(af0, bf[n][0], acc[m][n], 0, 0, 0);
                acc[m][n] = __builtin_amdgcn_mfma_f32_16x16x32_bf16(af1, bf[n][1], acc[m][n], 0, 0, 0);
            }
        }
    };

    // prologue: ks0 in X (written), ks1 in Y (in flight across first MFMA)
    issue(0, xa0, xa1, xb);
    issue(1, ya0, ya1, yb);
    writeb(0, xa0, xa1, xb);
    __syncthreads();
    int cur = 0;
    for (int ks = 0; ks < 12; ks += 2) {
        // even phase: consume ks (buf cur); X free, Y holds ks+1 (in flight)
        if (ks + 2 < 12) issue(ks + 2, xa0, xa1, xb);
        mfma_step(cur);
        writeb(cur ^ 1, ya0, ya1, yb);            // waits Y: issued 1 iter ago
        __syncthreads();
        cur ^= 1;
        // odd phase: consume ks+1; Y free, X holds ks+2 (in flight)
        if (ks + 3 < 12) issue(ks + 3, ya0, ya1, yb);
        mfma_step(cur);
        if (ks + 2 < 12) writeb(cur ^ 1, xa0, xa1, xb);  // waits X: issued 1 iter ago
        __syncthreads();
        cur ^= 1;
    }
    #pragma unroll
    for (int p = 0; p < 4; ++p) {
        float v = esq_p[p];
        v += __shfl_xor(v, 1); v += __shfl_xor(v, 2); v += __shfl_xor(v, 4);
        if (k8 == 0) esq_s[32 * p + g] = v;
    }
    __syncthreads();
    #pragma unroll
    for (int m = 0; m < 4; ++m) {
        int r0 = wr * 64 + m * 16 + (lane >> 4) * 4;
        float e0 = esq_s[r0], e1 = esq_s[r0 + 1], e2 = esq_s[r0 + 2], e3 = esq_s[r0 + 3];
        #pragma unroll
        for (int n = 0; n < 4; ++n) {
            int c = wc * 64 + n * 16 + (lane & 15);
            union { ushort4v v; unsigned int u[2]; } kv;
            kv.u[0] = f2bf2(e0 - 2.f * acc[m][n][0], e1 - 2.f * acc[m][n][1]);
            kv.u[1] = f2bf2(e2 - 2.f * acc[m][n][2], e3 - 2.f * acc[m][n][3]);
            *(ushort4v*)(cst + c * 136 + r0) = kv.v;
        }
    }
    __syncthreads();
    #pragma unroll
    for (int it = 0; it < 8; ++it) {
        int c = w * 32 + it * 4 + (lane >> 4);
        int r = (lane & 15) * 8;
        if (rowbase + r < M_TRAIN) {
            ushort8 v = *(const ushort8*)(cst + c * 136 + r);
            *(ushort8*)(keyT + (long)c * M_TRAIN + rowbase + r) = v;
        }
    }
}

__global__ void __launch_bounds__(256, 2) kB(const float* __restrict__ E,
        const unsigned short* __restrict__ bimg, unsigned short* __restrict__ keyT,
        const float* __restrict__ gram, const float* __restrict__ cpt,
        const float* __restrict__ whx, float* __restrict__ tsol,
        float* __restrict__ ct, float* __restrict__ out_scal,
        const float* __restrict__ pscore) {
    __shared__ __align__(16) char smem[68160];
    int b = blockIdx.x;
    if (b < 10)       cg_role(smem, gram, cpt, whx, tsol, ct, out_scal + 3, b);
    else if (b == 10) old_role(smem, pscore, gram, out_scal);
    else              P_role(smem, E, bimg, keyT, b - 11);
}

// ======================= kC: select(512) | ypred(512) =======================
__global__ void __launch_bounds__(256) kC(const unsigned short* __restrict__ keyT,
        int* __restrict__ cand, const float* __restrict__ te,
        const float* __restrict__ ct, const float* __restrict__ bhx,
        float* __restrict__ out) {
    __shared__ __align__(16) char smem[30720];
    int b = blockIdx.x, t = threadIdx.x;
    if (b < 512) {     // ---- select: per-(concept, quarter) top-16 ----
        int* sk  = (int*)smem;            // 2048
        int* si  = (int*)(smem + 8192);   // 2048
        int* wk  = (int*)(smem + 16384);
        int* wi  = (int*)(smem + 16400);
        int* wsl = (int*)(smem + 16416);
        int c = b >> 2, h = b & 3;
        const unsigned short* col = keyT + (long)c * M_TRAIN + h * CHUNKN;
        int base = h * CHUNKN;
        int tk[8], ti[8];
        #pragma unroll
        for (int i = 0; i < 8; ++i) { tk[i] = 0x7fffffff; ti[i] = 0x7fffffff; }
        for (int i = t; i < CHUNKN / 8; i += 256) {
            ushort8 v = *(const ushort8*)(col + i * 8);
            int idx = base + i * 8;
            #pragma unroll
            for (int q = 0; q < 8; ++q) {
                int cv = (int)v[q]; int ci = idx + q;
                if (cv < tk[7] || (cv == tk[7] && ci < ti[7])) {
                    #pragma unroll
                    for (int jj = 0; jj < 8; ++jj) {
                        bool sw = (cv < tk[jj]) || (cv == tk[jj] && ci < ti[jj]);
                        int ok = tk[jj]; int oi = ti[jj];
                        if (sw) { tk[jj] = cv; ti[jj] = ci; cv = ok; ci = oi; }
                    }
                }
            }
        }
        #pragma unroll
        for (int i = 0; i < 8; ++i) { sk[t * 8 + i] = tk[i]; si[t * 8 + i] = ti[i]; }
        __syncthreads();
        int lane = t & 63, w = t >> 6;
        for (int sel = 0; sel < CAND_PER; ++sel) {
            int bk = 0x7fffffff, bi = 0x7fffffff, bs = -1;
            #pragma unroll
            for (int i = 0; i < 8; ++i) {
                int s = t * 8 + i;
                int v = sk[s];
                if (v < bk || (v == bk && si[s] < bi)) { bk = v; bi = si[s]; bs = s; }
            }
            #pragma unroll
            for (int m = 32; m > 0; m >>= 1) {
                int ok = __shfl_xor(bk, m); int oi = __shfl_xor(bi, m); int os = __shfl_xor(bs, m);
                if (ok < bk || (ok == bk && oi < bi)) { bk = ok; bi = oi; bs = os; }
            }
            if (lane == 0) { wk[w] = bk; wi[w] = bi; wsl[w] = bs; }
            __syncthreads();
            if (t == 0) {
                int fk = wk[0], fi = wi[0], fs = wsl[0];
                for (int i = 1; i < 4; ++i)
                    if (wk[i] < fk || (wk[i] == fk && wi[i] < fi)) { fk = wk[i]; fi = wi[i]; fs = wsl[i]; }
                cand[(c * NCHUNK + h) * CAND_PER + sel] = fi;
                sk[fs] = 0x7fffffff; si[fs] = 0x7fffffff;
            }
            __syncthreads();
        }
    } else {           // ---- ypred ----
        float* ctT = (float*)smem;   // [NCLS][D_DIM]
        for (int o = t; o < D_DIM * NCLS; o += 256) {
            int j = o / D_DIM, d = o % D_DIM;
            ctT[j * D_DIM + d] = ct[d * NCLS + j];
        }
        __syncthreads();
        int r = t >> 5, l = t & 31;
        long row = (long)(b - 512) * 8 + r;
        const float* er = te + row * D_DIM;
        float acc[NCLS];
        #pragma unroll
        for (int j = 0; j < NCLS; ++j) acc[j] = 0.f;
        for (int d0 = l * 4; d0 < D_DIM; d0 += 128) {
            float4 e = *(const float4*)(er + d0);
            #pragma unroll
            for (int j = 0; j < NCLS; ++j) {
                float4 cc = *(const float4*)(&ctT[j * D_DIM + d0]);
                acc[j] += e.x*cc.x + e.y*cc.y + e.z*cc.z + e.w*cc.w;
            }
        }
        #pragma unroll
        for (int j = 0; j < NCLS; ++j) {
            #pragma unroll
            for (int m = 16; m > 0; m >>= 1) acc[j] += __shfl_xor(acc[j], m);
        }
        if (l == 0) {
            #pragma unroll
            for (int j = 0; j < NCLS; ++j) out[row * NCLS + j] = acc[j] + bhx[j];
        }
    }
}

// ======================= kD: refine(128) =======================
__global__ void __launch_bounds__(256) kD(const float* __restrict__ E,
        const float* __restrict__ conceptT, const int* __restrict__ cand,
        float* __restrict__ psum) {
    __shared__ float skey[NCT], sdot[NCT];
    __shared__ int sidx[NCT];
    int c = blockIdx.x, t = threadIdx.x;
    int g = t >> 2, l4 = t & 3;
    int idx = cand[c * NCT + g];
    const float* er = E + (long)idx * D_DIM;
    const float* cr = conceptT + c * D_DIM;
    float dot = 0.f, ss = 0.f;
    for (int d0 = l4 * 4; d0 < D_DIM; d0 += 16) {
        float4 e = *(const float4*)(er + d0);
        float4 cc = *(const float4*)(cr + d0);
        dot += e.x*cc.x + e.y*cc.y + e.z*cc.z + e.w*cc.w;
        ss  += e.x*e.x + e.y*e.y + e.z*e.z + e.w*e.w;
    }
    dot += __shfl_xor(dot, 1); dot += __shfl_xor(dot, 2);
    ss  += __shfl_xor(ss, 1);  ss  += __shfl_xor(ss, 2);
    if (l4 == 0) { skey[g] = ss - 2.f * dot; sdot[g] = dot; sidx[g] = idx; }
    __syncthreads();
    if (t == 0) {
        float sum = 0.f;
        unsigned long long used = 0ull;
        for (int s = 0; s < KSEL; ++s) {
            float bk = FLT_INF; int bi = 0x7fffffff, bs = 0;
            for (int i = 0; i < NCT; ++i) {
                if ((used >> i) & 1ull) continue;
                if (skey[i] < bk || (skey[i] == bk && sidx[i] < bi)) { bk = skey[i]; bi = sidx[i]; bs = i; }
            }
            used |= (1ull << bs);
            sum += sdot[bs];
        }
        psum[c] = sum;
    }
}

__global__ void k_finalize(const float* __restrict__ psum, float* __restrict__ out2) {
    __shared__ float red[128];
    int t = threadIdx.x;
    red[t] = psum[t];
    __syncthreads();
    for (int s = 64; s > 0; s >>= 1) { if (t < s) red[t] += red[t + s]; __syncthreads(); }
    if (t == 0) out2[0] = red[0] * (1.0f / (C_DIM * KSEL));
}

extern "C" void kernel_launch(void* const* d_in, const int* in_sizes, int n_in,
                              void* d_out, int out_size, void* d_ws, size_t ws_size,
                              hipStream_t stream) {
    (void)in_sizes; (void)n_in; (void)out_size; (void)ws_size;
    const float* te   = (const float*)d_in[0];  // 4096x768
    const float* cpt  = (const float*)d_in[1];  // 768x128
    const float* clus = (const float*)d_in[2];  // 500x100x768
    const float* tes  = (const float*)d_in[3];  // 100000x768
    const float* whx  = (const float*)d_in[4];  // 10x768
    const float* bhx  = (const float*)d_in[5];  // 10
    float* out = (float*)d_out;                 // 40960 y_pred + 4 scalars
    char* ws = (char*)d_ws;
    unsigned short* keyT  = (unsigned short*)(ws + WS_KEYT);
    unsigned short* bimg  = (unsigned short*)(ws + WS_BIMG);
    float* conceptT       = (float*)(ws + WS_CONT);
    float* gram           = (float*)(ws + WS_GRAM);
    float* pscore         = (float*)(ws + WS_PSCORE);
    float* ct             = (float*)(ws + WS_CT);
    int* cand             = (int*)(ws + WS_CAND);
    float* psum           = (float*)(ws + WS_PSUM);
    float* tsol           = (float*)(ws + WS_TSOL);

    kA<<<dim3(1448), dim3(256), 0, stream>>>(cpt, clus, conceptT, bimg, gram, pscore);
    kB<<<dim3(793),  dim3(256), 0, stream>>>(tes, bimg, keyT, gram, cpt, whx, tsol, ct,
                                             out + 40960, pscore);
    kC<<<dim3(1024), dim3(256), 0, stream>>>(keyT, cand, te, ct, bhx, out);
    kD<<<dim3(128),  dim3(256), 0, stream>>>(tes, conceptT, cand, psum);
    k_finalize<<<dim3(1), dim3(128), 0, stream>>>(psum, out + 40962);
}